// Round 1
// baseline (3941.218 us; speedup 1.0000x reference)
//
#include <hip/hip_runtime.h>

#define N_GRAPHS 32
#define NUM_NODES 2848
#define NTOT (N_GRAPHS * NUM_NODES)   // 91136
#define NE 1000000
#define KS 3
#define TL 5
#define HID 32
#define EPSV 1e-5f

// ---------------- graph preprocessing ----------------

__global__ void k_deg(const int* __restrict__ col, const float* __restrict__ w,
                      float* __restrict__ deg, int* __restrict__ indeg) {
    int e = blockIdx.x * blockDim.x + threadIdx.x;
    if (e < NE) {
        int c = col[e];
        atomicAdd(&deg[c], w[e]);
        atomicAdd(&indeg[c], 1);
    }
}

__global__ void k_dis(float* deg) {
    int i = blockIdx.x * blockDim.x + threadIdx.x;
    if (i < NTOT) {
        float d = deg[i];
        deg[i] = (d > 0.f) ? rsqrtf(d) : 0.f;
    }
}

__global__ void k_normk(const int* __restrict__ row, const int* __restrict__ col,
                        const float* __restrict__ w, const float* __restrict__ dis,
                        float* __restrict__ norm) {
    int e = blockIdx.x * blockDim.x + threadIdx.x;
    if (e < NE) {
        norm[e] = dis[row[e]] * w[e] * dis[col[e]];
    }
}

// exclusive scan of indeg[NTOT] -> offs[NTOT+1], single block of 1024
__global__ void k_scan(const int* __restrict__ in, int* __restrict__ out) {
    __shared__ int lds[1024];
    __shared__ int carry_s;
    if (threadIdx.x == 0) carry_s = 0;
    __syncthreads();
    const int nch = (NTOT + 1023) / 1024;
    for (int c = 0; c < nch; ++c) {
        int i = c * 1024 + threadIdx.x;
        int v = (i < NTOT) ? in[i] : 0;
        lds[threadIdx.x] = v;
        __syncthreads();
        for (int s = 1; s < 1024; s <<= 1) {
            int add = (threadIdx.x >= s) ? lds[threadIdx.x - s] : 0;
            __syncthreads();
            lds[threadIdx.x] += add;
            __syncthreads();
        }
        int incl = lds[threadIdx.x];
        int carry = carry_s;
        __syncthreads();
        if (i < NTOT) out[i] = carry + incl - v;
        if (threadIdx.x == 1023) carry_s = carry + lds[1023];
        __syncthreads();
    }
    if (threadIdx.x == 0) out[NTOT] = carry_s;
}

__global__ void k_fill(const int* __restrict__ row, const int* __restrict__ col,
                       const float* __restrict__ norm, int* __restrict__ cursor,
                       int* __restrict__ sidx, float* __restrict__ snorm) {
    int e = blockIdx.x * blockDim.x + threadIdx.x;
    if (e < NE) {
        int p = atomicAdd(&cursor[col[e]], 1);
        sidx[p] = row[e];
        snorm[p] = norm[e];
    }
}

// ---------------- ARMA layer kernels ----------------

// H[k,n,f] = sum_i A[(k),n,i] * W[k,i,f]
__global__ void k_kmm(const float* __restrict__ A, int a_kstride,
                      const float* __restrict__ W, float* __restrict__ H,
                      int Fin, int F) {
    int tid = blockIdx.x * blockDim.x + threadIdx.x;
    int total = KS * NTOT * F;
    if (tid >= total) return;
    int f = tid % F;
    int nk = tid / F;
    int node = nk % NTOT;
    int k = nk / NTOT;
    const float* a = A + k * a_kstride + node * Fin;
    const float* wk = W + (k * Fin) * F + f;
    float acc = 0.f;
    for (int i = 0; i < Fin; ++i) acc += a[i] * wk[i * F];
    H[tid] = acc;
}

// out[k,n,f] = relu( sum_{e in in(n)} snorm[e]*H[k,src[e],f]
//                    + sum_i xin[n,i]*rw_t[k,i,f] + b_t[k,f] )
__global__ void k_prop(const float* __restrict__ H, const float* __restrict__ xin,
                       const float* __restrict__ rw_t, const float* __restrict__ b_t,
                       const int* __restrict__ offs, const int* __restrict__ sidx,
                       const float* __restrict__ snorm, float* __restrict__ outb,
                       int Fin, int F) {
    int tid = blockIdx.x * blockDim.x + threadIdx.x;
    int total = KS * NTOT * F;
    if (tid >= total) return;
    int f = tid % F;
    int nk = tid / F;
    int node = nk % NTOT;
    int k = nk / NTOT;
    float acc = b_t[k * F + f];
    const float* rwk = rw_t + (k * Fin) * F + f;
    const float* xr = xin + node * Fin;
    for (int i = 0; i < Fin; ++i) acc += xr[i] * rwk[i * F];
    const float* hk = H + (k * NTOT) * F;
    int e0 = offs[node], e1 = offs[node + 1];
    for (int e = e0; e < e1; ++e)
        acc += snorm[e] * hk[sidx[e] * F + f];
    outb[tid] = fmaxf(acc, 0.f);
}

__global__ void k_mean(const float* __restrict__ outb, float* __restrict__ xo, int F) {
    int tid = blockIdx.x * blockDim.x + threadIdx.x;
    int total = NTOT * F;
    if (tid >= total) return;
    xo[tid] = (outb[tid] + outb[total + tid] + outb[2 * total + tid]) * (1.f / 3.f);
}

// ---------------- batchnorm ----------------

// stats[0..F) = sum, stats[F..2F) = sum of squares (atomically accumulated)
__global__ void k_bnstats(const float* __restrict__ x, float* __restrict__ stats, int F) {
    __shared__ float s1[256];
    __shared__ float s2[256];
    int tid = threadIdx.x;
    int gid = blockIdx.x * blockDim.x + tid;
    int stride = gridDim.x * blockDim.x;   // multiple of F (F is 1 or 32)
    int total = NTOT * F;
    float a = 0.f, b = 0.f;
    for (int i = gid; i < total; i += stride) {
        float v = x[i];
        a += v;
        b += v * v;
    }
    s1[tid] = a; s2[tid] = b;
    __syncthreads();
    for (int s = 128; s >= F; s >>= 1) {
        if (tid < s) { s1[tid] += s1[tid + s]; s2[tid] += s2[tid + s]; }
        __syncthreads();
    }
    if (tid < F) {
        atomicAdd(&stats[tid], s1[tid]);
        atomicAdd(&stats[F + tid], s2[tid]);
    }
}

__global__ void k_bnapply(float* __restrict__ x, const float* __restrict__ stats,
                          const float* __restrict__ g, const float* __restrict__ be, int F) {
    int i = blockIdx.x * blockDim.x + threadIdx.x;
    int total = NTOT * F;
    if (i >= total) return;
    int f = i % F;
    float m = stats[f] * (1.f / (float)NTOT);
    float v = stats[F + f] * (1.f / (float)NTOT) - m * m;
    float y = (x[i] - m) * rsqrtf(v + EPSV) * g[f] + be[f];
    x[i] = fmaxf(y, 0.f);
}

// ---------------- classifier + per-graph max ----------------

__global__ void k_final(const float* __restrict__ h, const float* __restrict__ cw,
                        const float* __restrict__ cb, float* __restrict__ out) {
    __shared__ float smax[256];
    int g = blockIdx.x;
    float cwv = cw[0], cbv = cb[0];
    float mx = -INFINITY;
    for (int i = threadIdx.x; i < NUM_NODES; i += blockDim.x) {
        int nidx = g * NUM_NODES + i;
        float v = h[nidx] * cwv + cbv;
        out[nidx] = v;
        mx = fmaxf(mx, v);
    }
    smax[threadIdx.x] = mx;
    __syncthreads();
    for (int s = 128; s >= 1; s >>= 1) {
        if (threadIdx.x < s) smax[threadIdx.x] = fmaxf(smax[threadIdx.x], smax[threadIdx.x + s]);
        __syncthreads();
    }
    if (threadIdx.x == 0) out[NTOT + g] = smax[0];
}

// ---------------- host launch ----------------

extern "C" void kernel_launch(void* const* d_in, const int* in_sizes, int n_in,
                              void* d_out, int out_size, void* d_ws, size_t ws_size,
                              hipStream_t stream) {
    const float* x   = (const float*)d_in[0];
    const int*   ei  = (const int*)d_in[1];
    const int*   row = ei;
    const int*   col = ei + NE;
    const float* wts = (const float*)d_in[2];
    // d_in[3] = batch (unused; graphs are contiguous blocks of NUM_NODES)
    const float* iw1 = (const float*)d_in[4];
    const float* w1  = (const float*)d_in[5];
    const float* rw1 = (const float*)d_in[6];
    const float* b1  = (const float*)d_in[7];
    const float* g1  = (const float*)d_in[8];
    const float* be1 = (const float*)d_in[9];
    const float* iw2 = (const float*)d_in[10];
    const float* w2  = (const float*)d_in[11];
    const float* rw2 = (const float*)d_in[12];
    const float* b2  = (const float*)d_in[13];
    const float* g2  = (const float*)d_in[14];
    const float* be2 = (const float*)d_in[15];
    const float* iw3 = (const float*)d_in[16];
    const float* w3  = (const float*)d_in[17];
    const float* rw3 = (const float*)d_in[18];
    const float* b3  = (const float*)d_in[19];
    const float* g3  = (const float*)d_in[20];
    const float* be3 = (const float*)d_in[21];
    const float* cw  = (const float*)d_in[22];
    const float* cb  = (const float*)d_in[23];
    float* out = (float*)d_out;

    char* p = (char*)d_ws;
    auto alloc = [&](size_t bytes) {
        char* r = p;
        p += (bytes + 255) & ~(size_t)255;
        return r;
    };
    float* deg    = (float*)alloc((size_t)NTOT * 4);        // deg -> dis in place
    float* norm   = (float*)alloc((size_t)NE * 4);
    int*   indeg  = (int*)alloc((size_t)NTOT * 4);
    int*   offs   = (int*)alloc((size_t)(NTOT + 1) * 4);
    int*   cursor = (int*)alloc((size_t)NTOT * 4);
    int*   sidx   = (int*)alloc((size_t)NE * 4);
    float* snorm  = (float*)alloc((size_t)NE * 4);
    float* H      = (float*)alloc((size_t)KS * NTOT * HID * 4);
    float* OB     = (float*)alloc((size_t)KS * NTOT * HID * 4);
    float* xa     = (float*)alloc((size_t)NTOT * HID * 4);
    float* xb     = (float*)alloc((size_t)NTOT * HID * 4);
    float* xc     = (float*)alloc((size_t)NTOT * 4);
    float* stats  = (float*)alloc(2 * HID * 4);
    if ((size_t)(p - (char*)d_ws) > ws_size) return;  // workspace too small

    const int tb = 256;
    const int ebl = (NE + tb - 1) / tb;
    const int nbl = (NTOT + tb - 1) / tb;

    hipMemsetAsync(deg, 0, (size_t)NTOT * 4, stream);
    hipMemsetAsync(indeg, 0, (size_t)NTOT * 4, stream);
    k_deg<<<ebl, tb, 0, stream>>>(col, wts, deg, indeg);
    k_dis<<<nbl, tb, 0, stream>>>(deg);
    k_normk<<<ebl, tb, 0, stream>>>(row, col, wts, deg, norm);
    k_scan<<<1, 1024, 0, stream>>>(indeg, offs);
    hipMemcpyAsync(cursor, offs, (size_t)NTOT * 4, hipMemcpyDeviceToDevice, stream);
    k_fill<<<ebl, tb, 0, stream>>>(row, col, norm, cursor, sidx, snorm);

    auto run_layer = [&](const float* xin, int Fin, int F, const float* iw, const float* ww,
                         const float* rw, const float* bb, const float* g, const float* be,
                         float* xout) {
        int total = KS * NTOT * F;
        int bl = (total + tb - 1) / tb;
        for (int t = 0; t < TL; ++t) {
            if (t == 0)
                k_kmm<<<bl, tb, 0, stream>>>(xin, 0, iw, H, Fin, F);
            else
                k_kmm<<<bl, tb, 0, stream>>>(OB, NTOT * F,
                                             ww + (size_t)(t - 1) * KS * F * F, H, F, F);
            k_prop<<<bl, tb, 0, stream>>>(H, xin, rw + (size_t)t * KS * Fin * F,
                                          bb + (size_t)t * KS * F, offs, sidx, snorm,
                                          OB, Fin, F);
        }
        int mtotal = NTOT * F;
        k_mean<<<(mtotal + tb - 1) / tb, tb, 0, stream>>>(OB, xout, F);
        hipMemsetAsync(stats, 0, (size_t)2 * F * 4, stream);
        k_bnstats<<<256, tb, 0, stream>>>(xout, stats, F);
        k_bnapply<<<(mtotal + tb - 1) / tb, tb, 0, stream>>>(xout, stats, g, be, F);
    };

    run_layer(x,  2,   HID, iw1, w1, rw1, b1, g1, be1, xa);
    run_layer(xa, HID, HID, iw2, w2, rw2, b2, g2, be2, xb);
    run_layer(xb, HID, 1,   iw3, w3, rw3, b3, g3, be3, xc);

    k_final<<<N_GRAPHS, 256, 0, stream>>>(xc, cw, cb, out);
}

// Round 2
// 1452.088 us; speedup vs baseline: 2.7142x; 2.7142x over previous
//
#include <hip/hip_runtime.h>

#define N_GRAPHS 32
#define NUM_NODES 2848
#define NTOT (N_GRAPHS * NUM_NODES)   // 91136
#define NE 1000000
#define KS 3
#define TL 5
#define HID 32
#define EPSV 1e-5f
#define SCAN_B 256
#define NBLK (NTOT / SCAN_B)          // 356 (exact)

// ---------------- graph preprocessing ----------------

__global__ void k_deg(const int* __restrict__ col, const float* __restrict__ w,
                      float* __restrict__ deg, int* __restrict__ indeg) {
    int e = blockIdx.x * blockDim.x + threadIdx.x;
    if (e < NE) {
        int c = col[e];
        atomicAdd(&deg[c], w[e]);
        atomicAdd(&indeg[c], 1);
    }
}

__global__ void k_dis(float* deg) {
    int i = blockIdx.x * blockDim.x + threadIdx.x;
    if (i < NTOT) {
        float d = deg[i];
        deg[i] = (d > 0.f) ? rsqrtf(d) : 0.f;
    }
}

// hierarchical exclusive scan of indeg -> offs
__global__ void k_scan1(const int* __restrict__ in, int* __restrict__ bsum) {
    __shared__ int s[SCAN_B];
    int i = blockIdx.x * SCAN_B + threadIdx.x;
    s[threadIdx.x] = (i < NTOT) ? in[i] : 0;
    __syncthreads();
    for (int st = SCAN_B / 2; st >= 1; st >>= 1) {
        if (threadIdx.x < st) s[threadIdx.x] += s[threadIdx.x + st];
        __syncthreads();
    }
    if (threadIdx.x == 0) bsum[blockIdx.x] = s[0];
}

__global__ void k_scan2(int* __restrict__ bsum) {
    __shared__ int s[512];
    int tid = threadIdx.x;
    int v = (tid < NBLK) ? bsum[tid] : 0;
    s[tid] = v;
    __syncthreads();
    for (int off = 1; off < 512; off <<= 1) {
        int a = (tid >= off) ? s[tid - off] : 0;
        __syncthreads();
        s[tid] += a;
        __syncthreads();
    }
    if (tid < NBLK) bsum[tid] = s[tid] - v;   // exclusive
}

__global__ void k_scan3(const int* __restrict__ in, const int* __restrict__ bsum,
                        int* __restrict__ offs) {
    __shared__ int s[SCAN_B];
    int i = blockIdx.x * SCAN_B + threadIdx.x;
    int v = (i < NTOT) ? in[i] : 0;
    s[threadIdx.x] = v;
    __syncthreads();
    for (int off = 1; off < SCAN_B; off <<= 1) {
        int a = (threadIdx.x >= off) ? s[threadIdx.x - off] : 0;
        __syncthreads();
        s[threadIdx.x] += a;
        __syncthreads();
    }
    if (i < NTOT) offs[i] = bsum[blockIdx.x] + s[threadIdx.x] - v;
    if (i == 0) offs[NTOT] = NE;
}

// fill CSR adjacency: adj[p] = (src, norm-bits), norm computed inline
__global__ void k_fill(const int* __restrict__ row, const int* __restrict__ col,
                       const float* __restrict__ w, const float* __restrict__ dis,
                       int* __restrict__ cursor, int2* __restrict__ adj) {
    int e = blockIdx.x * blockDim.x + threadIdx.x;
    if (e < NE) {
        int r = row[e], c = col[e];
        float nm = dis[r] * w[e] * dis[c];
        int p = atomicAdd(&cursor[c], 1);
        adj[p] = make_int2(r, __float_as_int(nm));
    }
}

// ---------------- ARMA layer kernels ----------------

// H0[n][k][f] = sum_i x[n][i] * iw[k][i][f]
template<int FIN, int F>
__global__ void k_init(const float* __restrict__ x, const float* __restrict__ iw,
                       float* __restrict__ H) {
    int tid = blockIdx.x * blockDim.x + threadIdx.x;
    if (tid >= NTOT * F) return;
    int f = tid % F;
    int n = tid / F;
    float xr[FIN];
#pragma unroll
    for (int i = 0; i < FIN; ++i) xr[i] = x[n * FIN + i];
    float* hn = H + (size_t)n * (KS * F);
#pragma unroll
    for (int k = 0; k < KS; ++k) {
        float acc = 0.f;
#pragma unroll
        for (int i = 0; i < FIN; ++i) acc += xr[i] * iw[(k * FIN + i) * F + f];
        hn[k * F + f] = acc;
    }
}

// Fused prop step: out = relu(gather + xin@rw_t + b_t), then either
//   - LAST: write mean over k to outp [NTOT, F]
//   - F==1: H_next[n][k] = out_k * W_t[k]
//   - else: LDS transform H_next[n][k][f] = sum_i out[k][n][i] * W_t[k][i][f]
template<int FIN, int F, bool LAST>
__global__ void k_prop(const float* __restrict__ H, const float* __restrict__ xin,
                       const float* __restrict__ rw_t, const float* __restrict__ b_t,
                       const float* __restrict__ W_t, const int* __restrict__ offs,
                       const int2* __restrict__ adj, float* __restrict__ outp) {
    constexpr int NPB = 256 / F;   // nodes per block (8 for F=32, 256 for F=1)
    int tid = threadIdx.x;
    int f = tid % F;
    int nl = tid / F;
    int node = blockIdx.x * NPB + nl;   // grid sized exactly

    float acc0 = b_t[0 * F + f], acc1 = b_t[1 * F + f], acc2 = b_t[2 * F + f];
#pragma unroll
    for (int i = 0; i < FIN; ++i) {
        float xv = xin[node * FIN + i];
        acc0 += xv * rw_t[(0 * FIN + i) * F + f];
        acc1 += xv * rw_t[(1 * FIN + i) * F + f];
        acc2 += xv * rw_t[(2 * FIN + i) * F + f];
    }
    int e0 = offs[node], e1 = offs[node + 1];
    for (int e = e0; e < e1; ++e) {
        int2 pr = adj[e];
        float w = __int_as_float(pr.y);
        const float* hr = H + (size_t)pr.x * (KS * F) + f;
        acc0 += w * hr[0];
        acc1 += w * hr[F];
        acc2 += w * hr[2 * F];
    }
    acc0 = fmaxf(acc0, 0.f);
    acc1 = fmaxf(acc1, 0.f);
    acc2 = fmaxf(acc2, 0.f);

    if constexpr (LAST) {
        outp[node * F + f] = (acc0 + acc1 + acc2) * (1.f / 3.f);
    } else if constexpr (F == 1) {
        float* hn = outp + (size_t)node * KS;
        hn[0] = acc0 * W_t[0];
        hn[1] = acc1 * W_t[1];
        hn[2] = acc2 * W_t[2];
    } else {
        __shared__ float so[NPB][KS][F];
        so[nl][0][f] = acc0;
        so[nl][1][f] = acc1;
        so[nl][2][f] = acc2;
        __syncthreads();
        float h0 = 0.f, h1 = 0.f, h2 = 0.f;
#pragma unroll
        for (int i = 0; i < F; ++i) {
            h0 += so[nl][0][i] * W_t[(0 * F + i) * F + f];
            h1 += so[nl][1][i] * W_t[(1 * F + i) * F + f];
            h2 += so[nl][2][i] * W_t[(2 * F + i) * F + f];
        }
        float* hn = outp + (size_t)node * (KS * F);
        hn[0 * F + f] = h0;
        hn[1 * F + f] = h1;
        hn[2 * F + f] = h2;
    }
}

// ---------------- batchnorm (+relu) ----------------

__global__ void k_bnstats(const float* __restrict__ x, float* __restrict__ stats, int F) {
    __shared__ float s1[256];
    __shared__ float s2[256];
    int tid = threadIdx.x;
    int gid = blockIdx.x * blockDim.x + tid;
    int stride = gridDim.x * blockDim.x;
    int total = NTOT * F;
    float a = 0.f, b = 0.f;
    for (int i = gid; i < total; i += stride) {
        float v = x[i];
        a += v;
        b += v * v;
    }
    s1[tid] = a; s2[tid] = b;
    __syncthreads();
    for (int s = 128; s >= F; s >>= 1) {
        if (tid < s) { s1[tid] += s1[tid + s]; s2[tid] += s2[tid + s]; }
        __syncthreads();
    }
    if (tid < F) {
        atomicAdd(&stats[tid], s1[tid]);
        atomicAdd(&stats[F + tid], s2[tid]);
    }
}

__global__ void k_bnapply(float* __restrict__ x, const float* __restrict__ stats,
                          const float* __restrict__ g, const float* __restrict__ be, int F) {
    int i = blockIdx.x * blockDim.x + threadIdx.x;
    int total = NTOT * F;
    if (i >= total) return;
    int f = i % F;
    float m = stats[f] * (1.f / (float)NTOT);
    float v = stats[F + f] * (1.f / (float)NTOT) - m * m;
    float y = (x[i] - m) * rsqrtf(v + EPSV) * g[f] + be[f];
    x[i] = fmaxf(y, 0.f);
}

// ---------------- classifier + per-graph max ----------------

__global__ void k_final(const float* __restrict__ h, const float* __restrict__ cw,
                        const float* __restrict__ cb, float* __restrict__ out) {
    __shared__ float smax[256];
    int g = blockIdx.x;
    float cwv = cw[0], cbv = cb[0];
    float mx = -INFINITY;
    for (int i = threadIdx.x; i < NUM_NODES; i += blockDim.x) {
        int nidx = g * NUM_NODES + i;
        float v = h[nidx] * cwv + cbv;
        out[nidx] = v;
        mx = fmaxf(mx, v);
    }
    smax[threadIdx.x] = mx;
    __syncthreads();
    for (int s = 128; s >= 1; s >>= 1) {
        if (threadIdx.x < s) smax[threadIdx.x] = fmaxf(smax[threadIdx.x], smax[threadIdx.x + s]);
        __syncthreads();
    }
    if (threadIdx.x == 0) out[NTOT + g] = smax[0];
}

// ---------------- host launch ----------------

extern "C" void kernel_launch(void* const* d_in, const int* in_sizes, int n_in,
                              void* d_out, int out_size, void* d_ws, size_t ws_size,
                              hipStream_t stream) {
    const float* x   = (const float*)d_in[0];
    const int*   ei  = (const int*)d_in[1];
    const int*   row = ei;
    const int*   col = ei + NE;
    const float* wts = (const float*)d_in[2];
    const float* iw1 = (const float*)d_in[4];
    const float* w1  = (const float*)d_in[5];
    const float* rw1 = (const float*)d_in[6];
    const float* b1  = (const float*)d_in[7];
    const float* g1  = (const float*)d_in[8];
    const float* be1 = (const float*)d_in[9];
    const float* iw2 = (const float*)d_in[10];
    const float* w2  = (const float*)d_in[11];
    const float* rw2 = (const float*)d_in[12];
    const float* b2  = (const float*)d_in[13];
    const float* g2  = (const float*)d_in[14];
    const float* be2 = (const float*)d_in[15];
    const float* iw3 = (const float*)d_in[16];
    const float* w3  = (const float*)d_in[17];
    const float* rw3 = (const float*)d_in[18];
    const float* b3  = (const float*)d_in[19];
    const float* g3  = (const float*)d_in[20];
    const float* be3 = (const float*)d_in[21];
    const float* cw  = (const float*)d_in[22];
    const float* cb  = (const float*)d_in[23];
    float* out = (float*)d_out;

    char* p = (char*)d_ws;
    auto alloc = [&](size_t bytes) {
        char* r = p;
        p += (bytes + 255) & ~(size_t)255;
        return r;
    };
    float* deg    = (float*)alloc((size_t)NTOT * 4);        // deg -> dis in place
    int*   indeg  = (int*)alloc((size_t)NTOT * 4);
    int*   bsum   = (int*)alloc((size_t)NBLK * 4);
    int*   offs   = (int*)alloc((size_t)(NTOT + 1) * 4);
    int*   cursor = (int*)alloc((size_t)NTOT * 4);
    int2*  adj    = (int2*)alloc((size_t)NE * 8);
    float* HA     = (float*)alloc((size_t)NTOT * KS * HID * 4);
    float* HB     = (float*)alloc((size_t)NTOT * KS * HID * 4);
    float* xa     = (float*)alloc((size_t)NTOT * HID * 4);
    float* xb     = (float*)alloc((size_t)NTOT * HID * 4);
    float* xc     = (float*)alloc((size_t)NTOT * 4);
    float* stats  = (float*)alloc(2 * HID * 4);
    if ((size_t)(p - (char*)d_ws) > ws_size) return;

    const int tb = 256;
    const int ebl = (NE + tb - 1) / tb;
    const int nbl = (NTOT + tb - 1) / tb;

    hipMemsetAsync(deg, 0, (size_t)NTOT * 4, stream);
    hipMemsetAsync(indeg, 0, (size_t)NTOT * 4, stream);
    k_deg<<<ebl, tb, 0, stream>>>(col, wts, deg, indeg);
    k_dis<<<nbl, tb, 0, stream>>>(deg);
    k_scan1<<<NBLK, SCAN_B, 0, stream>>>(indeg, bsum);
    k_scan2<<<1, 512, 0, stream>>>(bsum);
    k_scan3<<<NBLK, SCAN_B, 0, stream>>>(indeg, bsum, offs);
    hipMemcpyAsync(cursor, offs, (size_t)NTOT * 4, hipMemcpyDeviceToDevice, stream);
    k_fill<<<ebl, tb, 0, stream>>>(row, col, wts, deg, cursor, adj);

    // ---- layer 1: 2 -> 32 ----
    {
        constexpr int FIN = 2, F = HID;
        int gInit = (NTOT * F) / tb;
        int gProp = NTOT / (tb / F);
        k_init<FIN, F><<<gInit, tb, 0, stream>>>(x, iw1, HA);
        const float* Hc = HA; float* Hn = HB;
        for (int t = 0; t < TL - 1; ++t) {
            k_prop<FIN, F, false><<<gProp, tb, 0, stream>>>(
                Hc, x, rw1 + (size_t)t * KS * FIN * F, b1 + (size_t)t * KS * F,
                w1 + (size_t)t * KS * F * F, offs, adj, Hn);
            const float* tmp = Hc; Hc = Hn; Hn = (float*)tmp;
        }
        k_prop<FIN, F, true><<<gProp, tb, 0, stream>>>(
            Hc, x, rw1 + (size_t)(TL - 1) * KS * FIN * F, b1 + (size_t)(TL - 1) * KS * F,
            nullptr, offs, adj, xa);
        hipMemsetAsync(stats, 0, (size_t)2 * F * 4, stream);
        k_bnstats<<<256, tb, 0, stream>>>(xa, stats, F);
        k_bnapply<<<(NTOT * F) / tb, tb, 0, stream>>>(xa, stats, g1, be1, F);
    }
    // ---- layer 2: 32 -> 32 ----
    {
        constexpr int FIN = HID, F = HID;
        int gInit = (NTOT * F) / tb;
        int gProp = NTOT / (tb / F);
        k_init<FIN, F><<<gInit, tb, 0, stream>>>(xa, iw2, HA);
        const float* Hc = HA; float* Hn = HB;
        for (int t = 0; t < TL - 1; ++t) {
            k_prop<FIN, F, false><<<gProp, tb, 0, stream>>>(
                Hc, xa, rw2 + (size_t)t * KS * FIN * F, b2 + (size_t)t * KS * F,
                w2 + (size_t)t * KS * F * F, offs, adj, Hn);
            const float* tmp = Hc; Hc = Hn; Hn = (float*)tmp;
        }
        k_prop<FIN, F, true><<<gProp, tb, 0, stream>>>(
            Hc, xa, rw2 + (size_t)(TL - 1) * KS * FIN * F, b2 + (size_t)(TL - 1) * KS * F,
            nullptr, offs, adj, xb);
        hipMemsetAsync(stats, 0, (size_t)2 * F * 4, stream);
        k_bnstats<<<256, tb, 0, stream>>>(xb, stats, F);
        k_bnapply<<<(NTOT * F) / tb, tb, 0, stream>>>(xb, stats, g2, be2, F);
    }
    // ---- layer 3: 32 -> 1 ----
    {
        constexpr int FIN = HID, F = 1;
        int gInit = (NTOT * F + tb - 1) / tb;
        int gProp = NTOT / tb;
        k_init<FIN, F><<<gInit, tb, 0, stream>>>(xb, iw3, HA);
        const float* Hc = HA; float* Hn = HB;
        for (int t = 0; t < TL - 1; ++t) {
            k_prop<FIN, F, false><<<gProp, tb, 0, stream>>>(
                Hc, xb, rw3 + (size_t)t * KS * FIN * F, b3 + (size_t)t * KS * F,
                w3 + (size_t)t * KS * F * F, offs, adj, Hn);
            const float* tmp = Hc; Hc = Hn; Hn = (float*)tmp;
        }
        k_prop<FIN, F, true><<<gProp, tb, 0, stream>>>(
            Hc, xb, rw3 + (size_t)(TL - 1) * KS * FIN * F, b3 + (size_t)(TL - 1) * KS * F,
            nullptr, offs, adj, xc);
        hipMemsetAsync(stats, 0, (size_t)2 * F * 4, stream);
        k_bnstats<<<256, tb, 0, stream>>>(xc, stats, F);
        k_bnapply<<<(NTOT * F + tb - 1) / tb, tb, 0, stream>>>(xc, stats, g3, be3, F);
    }

    k_final<<<N_GRAPHS, 256, 0, stream>>>(xc, cw, cb, out);
}